// Round 15
// baseline (256.200 us; speedup 1.0000x reference)
//
#include <hip/hip_runtime.h>
#include <hip/hip_bf16.h>
#include <math.h>

// Problem constants (B=1)
#define TT 512      // tokens = B*S
#define DD 1024     // model dim
#define FF 4096     // ffn dim
#define EE 8        // experts
#define RR 16       // lora rank
#define KKSEL 2     // top-k
#define SCALING 2.0f
#define EPSV 1e-6f
#define DFC 128     // delta kernel f-chunk
#define SCHUNK 32   // delta kernel slot-chunk
#define NQITEMS 1536  // 1024 w1|w3 panel items + 512 w2 items (8192 elems each)

typedef unsigned short u16;
typedef short bhalf8 __attribute__((ext_vector_type(8)));
typedef float floatx4 __attribute__((ext_vector_type(4)));
typedef float f32x4 __attribute__((ext_vector_type(4)));
typedef unsigned short u16x8 __attribute__((ext_vector_type(8)));

__device__ __forceinline__ u16 f2b(float f) {
    unsigned x = __builtin_bit_cast(unsigned, f);
    unsigned r = (x + 0x7fffu + ((x >> 16) & 1u)) >> 16;
    return (u16)r;
}
__device__ __forceinline__ float b2f(u16 b) {
    unsigned x = ((unsigned)b) << 16;
    return __builtin_bit_cast(float, x);
}

__device__ __forceinline__ void gl_lds16(const void* g, void* l) {
    __builtin_amdgcn_global_load_lds(
        (const __attribute__((address_space(1))) void*)g,
        (__attribute__((address_space(3))) void*)l, 16, 0, 0);
}

// ================== fused front kernel ==================
// blocks [0,512): prep token, then help-drain convert queue
// blocks [512,1024): help-drain queue, wait for B-panel + prep, run GEMM1 tile
// block 1024: help-drain, wait prep, build expert lists
// Convert item i<1024: w1|w3 panel p=i>>4, 8 rows (panel-aligned for GEMM1 flags)
// Convert item i>=1024: w2 chunk (no flag; consumed 2 kernels later)
__global__ __launch_bounds__(256) void fused1_k(const float* __restrict__ x,
                                                const float* __restrict__ nw,
                                                const float* __restrict__ gw,
                                                const float* __restrict__ a1,
                                                const float* __restrict__ a3,
                                                const float* __restrict__ w1,
                                                const float* __restrict__ w3,
                                                const float* __restrict__ w2,
                                                u16* __restrict__ tb,
                                                float* __restrict__ topw,
                                                int* __restrict__ topi,
                                                float* __restrict__ s1,
                                                float* __restrict__ s3,
                                                u16* __restrict__ wB,
                                                u16* __restrict__ hb,
                                                int* __restrict__ flags,
                                                int* __restrict__ lists,
                                                int* __restrict__ counts) {
    __shared__ u16 sh[3 * 2048 + 3 * 4096];   // 36 KB: GEMM As|Bs, overlaid by prep tL
    __shared__ int qItS;
    __shared__ float red[12];
    __shared__ int sE[2];
    int tid = threadIdx.x;
    int bid = blockIdx.x;
    int* qHead = flags;
    int* prepDone = flags + 1;
    int* panelCnt = flags + 64;

    auto drain_queue = [&]() {
        const int FD = FF * DD;
        for (;;) {
            if (tid == 0) qItS = atomicAdd(qHead, 1);
            __syncthreads();
            int it = qItS;
            __syncthreads();
            if (it >= NQITEMS) break;
            const float* src;
            u16* dst;
            int p = -1;
            if (it < 1024) {               // w1|w3 panel item: 8 rows of wB
                p = it >> 4;
                int row0 = p * 128 + (it & 15) * 8;
                src = (row0 < FF) ? (w1 + (size_t)row0 * DD) : (w3 + (size_t)(row0 - FF) * DD);
                dst = wB + (size_t)row0 * DD;
            } else {                        // w2 chunk: 8192 contiguous elems
                int c = it - 1024;
                src = w2 + (size_t)c * 8192;
                dst = wB + (size_t)2 * FD + (size_t)c * 8192;
            }
            f32x4 v[8];
            #pragma unroll
            for (int j = 0; j < 8; j++)
                v[j] = __builtin_nontemporal_load((const f32x4*)(src + j * 1024) + tid);
            #pragma unroll
            for (int j = 0; j < 8; j++) {
                ushort4 o = { f2b(v[j][0]), f2b(v[j][1]), f2b(v[j][2]), f2b(v[j][3]) };
                *(ushort4*)(dst + j * 1024 + tid * 4) = o;
            }
            __syncthreads();               // all stores issued+acked before flag
            if (p >= 0 && tid == 0)
                __hip_atomic_fetch_add(&panelCnt[p], 1, __ATOMIC_RELEASE, __HIP_MEMORY_SCOPE_AGENT);
        }
    };

    if (bid < TT) {
        // ---------------- prep (token = bid) ----------------
        int tok = bid;
        int wave = tid >> 6, lane = tid & 63;
        float* tL = (float*)sh;
        const float* xr = x + (size_t)tok * DD;
        float xv[4];
        float ss = 0.f;
        #pragma unroll
        for (int i = 0; i < 4; i++) { xv[i] = xr[tid + 256 * i]; ss += xv[i] * xv[i]; }
        #pragma unroll
        for (int o = 32; o > 0; o >>= 1) ss += __shfl_down(ss, o);
        if (lane == 0) red[wave] = ss;
        __syncthreads();
        if (tid == 0) red[8] = rsqrtf((red[0] + red[1] + red[2] + red[3]) * (1.0f / DD) + EPSV);
        __syncthreads();
        float rs = red[8];
        #pragma unroll
        for (int i = 0; i < 4; i++) {
            float v = xv[i] * rs * nw[tid + 256 * i];
            tL[tid + 256 * i] = v;
            tb[(size_t)tok * DD + tid + 256 * i] = f2b(v);
        }
        __syncthreads();
        {
            const float* g0 = gw + (size_t)(2 * wave) * DD;
            const float* g1 = g0 + DD;
            float a0 = 0.f, a1v = 0.f;
            for (int d = lane; d < DD; d += 64) {
                float tv = tL[d];
                a0 = fmaf(tv, g0[d], a0);
                a1v = fmaf(tv, g1[d], a1v);
            }
            #pragma unroll
            for (int o = 32; o > 0; o >>= 1) { a0 += __shfl_down(a0, o); a1v += __shfl_down(a1v, o); }
            if (lane == 0) { red[2 * wave] = a0; red[2 * wave + 1] = a1v; }
        }
        __syncthreads();
        if (tid == 0) {
            float m = red[0];
            #pragma unroll
            for (int e = 1; e < EE; e++) m = fmaxf(m, red[e]);
            float p[EE];
            #pragma unroll
            for (int e = 0; e < EE; e++) p[e] = expf(red[e] - m);
            int i0 = 0; float v0 = p[0];
            for (int e = 1; e < EE; e++) if (p[e] > v0) { v0 = p[e]; i0 = e; }
            int i1 = -1; float v1 = -1.f;
            for (int e = 0; e < EE; e++) { if (e == i0) continue; if (p[e] > v1) { v1 = p[e]; i1 = e; } }
            float inv = 1.f / (v0 + v1);
            topi[tok * KKSEL + 0] = i0;
            topi[tok * KKSEL + 1] = i1;
            topw[tok * KKSEL + 0] = v0 * inv;
            topw[tok * KKSEL + 1] = v1 * inv;
            sE[0] = i0; sE[1] = i1;
        }
        __syncthreads();
        {
            int half = wave >> 1, ten = wave & 1;
            int slot = tok * 2 + half;
            int e = sE[half];
            const float* ap = ten ? a3 : a1;
            float* sp = ten ? s3 : s1;
            float tv[16];
            #pragma unroll
            for (int i = 0; i < 16; i++) tv[i] = tL[lane + 64 * i];
            const float* ab = ap + (size_t)e * RR * DD;
            #pragma unroll
            for (int r = 0; r < RR; r++) {
                const float* ar = ab + (size_t)r * DD;
                float c = 0.f;
                #pragma unroll
                for (int i = 0; i < 16; i++) c = fmaf(tv[i], ar[lane + 64 * i], c);
                #pragma unroll
                for (int o = 32; o > 0; o >>= 1) c += __shfl_down(c, o);
                if (lane == 0) sp[slot * RR + r] = SCALING * c;
            }
        }
        __syncthreads();
        if (tid == 0)
            __hip_atomic_fetch_add(prepDone, 1, __ATOMIC_RELEASE, __HIP_MEMORY_SCOPE_AGENT);
        drain_queue();
        return;
    }

    if (bid == TT + 512) {
        // ---------------- build_lists (after helping drain) ----------------
        drain_queue();
        if (tid == 0) {
            while (__hip_atomic_load(prepDone, __ATOMIC_ACQUIRE, __HIP_MEMORY_SCOPE_AGENT) < TT)
                __builtin_amdgcn_s_sleep(8);
        }
        __syncthreads();
        int* cnt = (int*)sh;
        if (tid < EE) cnt[tid] = 0;
        __syncthreads();
        for (int s = tid; s < TT * KKSEL; s += 256) atomicAdd(&cnt[topi[s]], 1);
        __syncthreads();
        if (tid < EE) { counts[tid] = cnt[tid]; cnt[tid] = 0; }
        __syncthreads();
        for (int s = tid; s < TT * KKSEL; s += 256) {
            int e = topi[s];
            int p = atomicAdd(&cnt[e], 1);
            lists[e * 1024 + p] = s;
        }
        return;
    }

    // ---------------- GEMM1 tile (help drain first) ----------------
    drain_queue();
    int t = bid - TT;
    int gx = t >> 3, gy = t & 7;           // consecutive blocks share B panel gx
    if (tid == 0) {
        for (;;) {
            int pc = __hip_atomic_load(&panelCnt[gx], __ATOMIC_ACQUIRE, __HIP_MEMORY_SCOPE_AGENT);
            int pd = __hip_atomic_load(prepDone, __ATOMIC_ACQUIRE, __HIP_MEMORY_SCOPE_AGENT);
            if (pc >= 16 && pd >= TT) break;
            __builtin_amdgcn_s_sleep(8);
        }
    }
    __syncthreads();

    u16* As = sh;                 // [3][64*32]
    u16* Bs = sh + 3 * 2048;      // [3][128*32]
    int w = tid >> 6, lane = tid & 63;
    int wr = w >> 1, wc = w & 1;
    int lr = lane & 15, ks = lane >> 4;
    const int K = DD, N = 2 * FF;
    int nk = K / 32;              // 32
    int m0 = gy * 64, n0 = gx * 128;

    int row = tid >> 2;
    int inb = (tid & 3) * 16;
    size_t rb = (size_t)K * 2;
    const char* Ag  = (const char*)tb + (size_t)(m0 + row) * rb + inb;
    const char* Bg  = (const char*)wB + (size_t)(n0 + row) * rb + inb;
    const char* Bg2 = Bg + 64 * rb;

    floatx4 zero4 = {0.f, 0.f, 0.f, 0.f};
    floatx4 acc[2][4];
    #pragma unroll
    for (int i = 0; i < 2; i++)
        #pragma unroll
        for (int j = 0; j < 4; j++) acc[i][j] = zero4;

    auto stage = [&](int buf, int kt) {
        size_t kb = (size_t)kt * 64;
        gl_lds16(Ag + kb, &As[buf * 2048 + w * 512]);
        gl_lds16(Bg + kb, &Bs[buf * 4096 + w * 512]);
        gl_lds16(Bg2 + kb, &Bs[buf * 4096 + 2048 + w * 512]);
    };
    auto compute = [&](int buf) {
        bhalf8 af[2], bf[4];
        #pragma unroll
        for (int i = 0; i < 2; i++)
            af[i] = *(const bhalf8*)&As[buf * 2048 + (wr * 32 + i * 16 + lr) * 32 + ks * 8];
        #pragma unroll
        for (int j = 0; j < 4; j++)
            bf[j] = *(const bhalf8*)&Bs[buf * 4096 + (wc * 64 + j * 16 + lr) * 32 + ks * 8];
        #pragma unroll
        for (int i = 0; i < 2; i++)
            #pragma unroll
            for (int j = 0; j < 4; j++)
                acc[i][j] = __builtin_amdgcn_mfma_f32_16x16x32_bf16(af[i], bf[j], acc[i][j], 0, 0, 0);
    };

    stage(0, 0);
    stage(1, 1);
    asm volatile("s_waitcnt vmcnt(3)" ::: "memory");
    __builtin_amdgcn_s_barrier();

    int cur = 0;
    for (int kt = 0; kt < nk; ++kt) {
        int pre = cur + 2; if (pre >= 3) pre -= 3;
        if (kt + 2 < nk) stage(pre, kt + 2);
        compute(cur);
        asm volatile("s_waitcnt lgkmcnt(0)" ::: "memory");
        if (kt + 1 < nk) {
            if (kt + 2 < nk) asm volatile("s_waitcnt vmcnt(3)" ::: "memory");
            else             asm volatile("s_waitcnt vmcnt(0)" ::: "memory");
            __builtin_amdgcn_s_barrier();
        }
        cur = (cur + 1 == 3) ? 0 : cur + 1;
    }

    int crow = (lane >> 4) * 4;
    #pragma unroll
    for (int i = 0; i < 2; i++) {
        #pragma unroll
        for (int j = 0; j < 4; j++) {
            int r0 = m0 + wr * 32 + i * 16 + crow;
            int c0 = n0 + wc * 64 + j * 16 + lr;
            #pragma unroll
            for (int mm = 0; mm < 4; mm++)
                hb[(size_t)(r0 + mm) * N + c0] = f2b(acc[i][j][mm]);
        }
    }
}

// ---- expert-major LoRA-up delta + SwiGLU: actb[slot,f] = silu(h1+d1)*(h3+d3) ------
__global__ __launch_bounds__(256) void delta_act_k(const float* __restrict__ b1,
                                                   const float* __restrict__ b3,
                                                   const float* __restrict__ s1,
                                                   const float* __restrict__ s3,
                                                   const int* __restrict__ lists,
                                                   const int* __restrict__ counts,
                                                   const u16* __restrict__ hb,
                                                   u16* __restrict__ actb) {
    int e = blockIdx.y, f0 = blockIdx.x * DFC;
    int st = blockIdx.z * SCHUNK;
    int n = counts[e];
    if (st >= n) return;
    int gn = min(SCHUNK, n - st);
    __shared__ float bL[2][16 * 132];
    __shared__ float sG[2][SCHUNK * 16];
    __shared__ int   sSlot[SCHUNK];
    int tid = threadIdx.x;
    int g = tid >> 7, f = tid & 127;
    const int* lp = lists + e * 1024 + st;
    {
        const float* bsrc1 = b1 + ((size_t)e * FF + f0) * RR;
        const float* bsrc3 = b3 + ((size_t)e * FF + f0) * RR;
        #pragma unroll
        for (int i = tid; i < DFC * 16; i += 256) {
            int fi = i >> 4, r = i & 15;
            bL[0][r * 132 + fi] = bsrc1[i];
            bL[1][r * 132 + fi] = bsrc3[i];
        }
        int sl_l = (tid & 127) >> 2, q = tid & 3;
        if (sl_l < gn) {
            int slot = lp[sl_l];
            const float* ssrc = g ? s3 : s1;
            *(float4*)&sG[g][sl_l * 16 + q * 4] = *(const float4*)&ssrc[slot * RR + q * 4];
            if (g == 0 && q == 0) sSlot[sl_l] = slot;
        }
    }
    __syncthreads();
    for (int ii = g; ii < gn; ii += 2) {
        int slot = sSlot[ii];
        int tok = slot >> 1;
        float h1b = b2f(hb[(size_t)tok * (2 * FF) + f0 + f]);
        float h3b = b2f(hb[(size_t)tok * (2 * FF) + FF + f0 + f]);
        const float* sp1 = &sG[0][ii * 16];
        const float* sp3 = &sG[1][ii * 16];
        float d1 = 0.f, d3 = 0.f;
        #pragma unroll
        for (int r = 0; r < RR; r++) {
            d1 = fmaf(sp1[r], bL[0][r * 132 + f], d1);
            d3 = fmaf(sp3[r], bL[1][r * 132 + f], d3);
        }
        float h1 = h1b + d1, h3 = h3b + d3;
        float sig = 1.f / (1.f + expf(-h1));
        actb[(size_t)slot * FF + f0 + f] = f2b(h1 * sig * h3);
    }
}

// ---------------- GEMM2: NT GEMM, 64x128 tile, BK=32, split-K=8 ----------------
__global__ __launch_bounds__(256) void gemm2_k(const u16* __restrict__ A,
                                               const u16* __restrict__ B,
                                               float* __restrict__ C0,
                                               int M, int N, int K) {
    __shared__ u16 As[3][64 * 32];
    __shared__ u16 Bs[3][128 * 32];
    int tid = threadIdx.x;
    int w = tid >> 6, lane = tid & 63;
    int wr = w >> 1, wc = w & 1;
    int lr = lane & 15, ks = lane >> 4;
    int z = blockIdx.z;
    int kc = K / 8, k0s = z * kc;
    int nk = kc / 32;
    int m0 = blockIdx.y * 64, n0 = blockIdx.x * 128;

    int row = tid >> 2;
    int inb = (tid & 3) * 16;
    size_t rb = (size_t)K * 2;
    const char* Ag  = (const char*)A + (size_t)(m0 + row) * rb + inb + (size_t)k0s * 2;
    const char* Bg  = (const char*)B + (size_t)(n0 + row) * rb + inb + (size_t)k0s * 2;
    const char* Bg2 = Bg + 64 * rb;

    floatx4 zero4 = {0.f, 0.f, 0.f, 0.f};
    floatx4 acc[2][4];
    #pragma unroll
    for (int i = 0; i < 2; i++)
        #pragma unroll
        for (int j = 0; j < 4; j++) acc[i][j] = zero4;

    auto stage = [&](int buf, int kt) {
        size_t kb = (size_t)kt * 64;
        gl_lds16(Ag + kb, &As[buf][w * 512]);
        gl_lds16(Bg + kb, &Bs[buf][w * 512]);
        gl_lds16(Bg2 + kb, &Bs[buf][2048 + w * 512]);
    };
    auto compute = [&](int buf) {
        bhalf8 af[2], bf[4];
        #pragma unroll
        for (int i = 0; i < 2; i++)
            af[i] = *(const bhalf8*)&As[buf][(wr * 32 + i * 16 + lr) * 32 + ks * 8];
        #pragma unroll
        for (int j = 0; j < 4; j++)
            bf[j] = *(const bhalf8*)&Bs[buf][(wc * 64 + j * 16 + lr) * 32 + ks * 8];
        #pragma unroll
        for (int i = 0; i < 2; i++)
            #pragma unroll
            for (int j = 0; j < 4; j++)
                acc[i][j] = __builtin_amdgcn_mfma_f32_16x16x32_bf16(af[i], bf[j], acc[i][j], 0, 0, 0);
    };

    stage(0, 0);
    stage(1, 1);
    asm volatile("s_waitcnt vmcnt(3)" ::: "memory");
    __builtin_amdgcn_s_barrier();

    int cur = 0;
    for (int kt = 0; kt < nk; ++kt) {
        int pre = cur + 2; if (pre >= 3) pre -= 3;
        if (kt + 2 < nk) stage(pre, kt + 2);
        compute(cur);
        asm volatile("s_waitcnt lgkmcnt(0)" ::: "memory");
        if (kt + 1 < nk) {
            if (kt + 2 < nk) asm volatile("s_waitcnt vmcnt(3)" ::: "memory");
            else             asm volatile("s_waitcnt vmcnt(0)" ::: "memory");
            __builtin_amdgcn_s_barrier();
        }
        cur = (cur + 1 == 3) ? 0 : cur + 1;
    }

    float* Cf = C0 + (size_t)z * M * N;
    int crow = (lane >> 4) * 4;
    #pragma unroll
    for (int i = 0; i < 2; i++) {
        #pragma unroll
        for (int j = 0; j < 4; j++) {
            int r0 = m0 + wr * 32 + i * 16 + crow;
            int c0 = n0 + wc * 64 + j * 16 + lr;
            #pragma unroll
            for (int mm = 0; mm < 4; mm++)
                Cf[(size_t)(r0 + mm) * N + c0] = acc[i][j][mm];
        }
    }
}

// ---- s2 (both slots of a token) + mixed[t,f] = w0*act[2t,f] + w1*act[2t+1,f] -------
__global__ __launch_bounds__(256) void s2mix_k(const u16* __restrict__ actb,
                                               const float* __restrict__ a2,
                                               const int* __restrict__ topi,
                                               const float* __restrict__ topw,
                                               float* __restrict__ s2,
                                               u16* __restrict__ mixedb) {
    int tok = blockIdx.x;
    int tid = threadIdx.x, wave = tid >> 6, lane = tid & 63;
    int slot = tok * 2 + (wave >> 1);
    int e = topi[slot];
    const u16* ar = actb + (size_t)slot * FF;
    float av[64];
    #pragma unroll
    for (int i = 0; i < 16; i++) {
        ushort4 u = *(const ushort4*)(ar + lane * 4 + 256 * i);
        av[i * 4 + 0] = b2f(u.x); av[i * 4 + 1] = b2f(u.y);
        av[i * 4 + 2] = b2f(u.z); av[i * 4 + 3] = b2f(u.w);
    }
    #pragma unroll
    for (int rr = 0; rr < 8; rr++) {
        int r = (wave & 1) * 8 + rr;
        const float* a2p = a2 + ((size_t)e * RR + r) * FF;
        float c = 0.f;
        #pragma unroll
        for (int i = 0; i < 16; i++) {
            float4 w4 = *(const float4*)(a2p + lane * 4 + 256 * i);
            c = fmaf(av[i * 4 + 0], w4.x, c);
            c = fmaf(av[i * 4 + 1], w4.y, c);
            c = fmaf(av[i * 4 + 2], w4.z, c);
            c = fmaf(av[i * 4 + 3], w4.w, c);
        }
        #pragma unroll
        for (int o = 32; o > 0; o >>= 1) c += __shfl_down(c, o);
        if (lane == 0) s2[slot * RR + r] = SCALING * c;
    }
    float w0 = topw[tok * 2], w1v = topw[tok * 2 + 1];
    const u16* a0 = actb + (size_t)(tok * 2) * FF;
    const u16* a1p = a0 + FF;
    #pragma unroll
    for (int it = 0; it < 2; it++) {
        int f = tid * 8 + it * 2048;
        u16x8 v0 = *(const u16x8*)(a0 + f);
        u16x8 v1 = *(const u16x8*)(a1p + f);
        u16x8 o;
        #pragma unroll
        for (int q = 0; q < 8; q++)
            o[q] = f2b(w0 * b2f(v0[q]) + w1v * b2f(v1[q]));
        *(u16x8*)(mixedb + (size_t)tok * FF + f) = o;
    }
}

// ---- combine: out[t,d] = sum_z downP[z,t,d] + sum_k w_k * (s2[slot_k] . b2[e_k,d,:]) --
__global__ __launch_bounds__(256) void combine_k(const float* __restrict__ downP,
                                                 const float* __restrict__ s2,
                                                 const float* __restrict__ b2,
                                                 const float* __restrict__ topw,
                                                 const int* __restrict__ topi,
                                                 float* __restrict__ out) {
    int tok = blockIdx.x;
    for (int d = threadIdx.x; d < DD; d += 256) {
        float v = 0.f;
        #pragma unroll
        for (int zz = 0; zz < 8; zz++)
            v += downP[(size_t)zz * TT * DD + (size_t)tok * DD + d];
        #pragma unroll
        for (int k = 0; k < KKSEL; k++) {
            int slot = tok * KKSEL + k;
            int e = topi[slot];
            float w = topw[slot];
            const float* b2p = b2 + ((size_t)e * DD + d) * RR;
            const float* s2p = s2 + slot * RR;
            float l = 0.f;
            #pragma unroll
            for (int r = 0; r < RR; r++) l = fmaf(s2p[r], b2p[r], l);
            v += w * l;
        }
        out[(size_t)tok * DD + d] = v;
    }
}

extern "C" void kernel_launch(void* const* d_in, const int* in_sizes, int n_in,
                              void* d_out, int out_size, void* d_ws, size_t ws_size,
                              hipStream_t stream) {
    const float* x  = (const float*)d_in[0];
    const float* nw = (const float*)d_in[1];
    const float* w1 = (const float*)d_in[2];
    const float* w3 = (const float*)d_in[3];
    const float* w2 = (const float*)d_in[4];
    const float* gw = (const float*)d_in[5];
    const float* a1 = (const float*)d_in[6];
    const float* b1 = (const float*)d_in[7];
    const float* a3 = (const float*)d_in[8];
    const float* b3 = (const float*)d_in[9];
    const float* a2 = (const float*)d_in[10];
    const float* b2 = (const float*)d_in[11];
    float* out = (float*)d_out;

    // workspace layout (~61 MB), all chunks 16B-aligned
    float* downP = (float*)d_ws;                          // 8 * 512*1024 f32 (16MB)
    float* s1    = downP + (size_t)8 * TT * DD;
    float* s3    = s1 + (size_t)TT * KKSEL * RR;
    float* s2    = s3 + (size_t)TT * KKSEL * RR;
    float* topw  = s2 + (size_t)TT * KKSEL * RR;
    int*   topi  = (int*)(topw + TT * KKSEL);
    int*   lists = topi + TT * KKSEL;                     // 8*1024
    int*   counts= lists + EE * 1024;                     // 16
    int*   flags = counts + 16;                           // 128 ints (qHead, prepDone, panelCnt[64])
    u16*   tb    = (u16*)(flags + 128);                   // 512*1024
    u16*   wB    = tb + (size_t)TT * DD;                  // [w1b | w3b | w2b] 3*4096*1024
    u16*   w2b   = wB + (size_t)2 * FF * DD;
    u16*   hb    = w2b + (size_t)DD * FF;                 // 512*8192 (h1|h3 per token)
    u16*   actb  = hb + (size_t)TT * 2 * FF;              // 1024*4096
    u16*   mixedb= actb + (size_t)TT * KKSEL * FF;        // 512*4096

    hipMemsetAsync(flags, 0, 128 * sizeof(int), stream);
    // fused: prep (512) + convert queue + GEMM1 (512) + build_lists (1)
    fused1_k<<<TT + 512 + 1, 256, 0, stream>>>(
        x, nw, gw, a1, a3, w1, w3, w2,
        tb, topw, topi, s1, s3, wB, hb, flags, lists, counts);
    delta_act_k<<<dim3(FF / DFC, EE, 32), 256, 0, stream>>>(
        b1, b3, s1, s3, lists, counts, hb, actb);
    s2mix_k<<<TT, 256, 0, stream>>>(actb, a2, topi, topw, s2, mixedb);
    gemm2_k<<<dim3(DD / 128, TT / 64, 8), 256, 0, stream>>>(
        mixedb, w2b, downP, TT, DD, FF);
    combine_k<<<TT, 256, 0, stream>>>(downP, s2, b2, topw, topi, out);
}

// Round 16
// 101.038 us; speedup vs baseline: 2.5357x; 2.5357x over previous
//
#include <hip/hip_runtime.h>
#include <hip/hip_bf16.h>
#include <math.h>

// Problem constants (B=1)
#define TT 512      // tokens = B*S
#define DD 1024     // model dim
#define FF 4096     // ffn dim
#define EE 8        // experts
#define RR 16       // lora rank
#define KKSEL 2     // top-k
#define SCALING 2.0f
#define EPSV 1e-6f
#define DFC 128     // delta kernel f-chunk
#define SCHUNK 32   // delta kernel slot-chunk
#define CVTB 6144   // convert blocks (2048 per weight matrix)

typedef unsigned short u16;
typedef short bhalf8 __attribute__((ext_vector_type(8)));
typedef float floatx4 __attribute__((ext_vector_type(4)));
typedef unsigned short u16x8 __attribute__((ext_vector_type(8)));

__device__ __forceinline__ u16 f2b(float f) {
    unsigned x = __builtin_bit_cast(unsigned, f);
    unsigned r = (x + 0x7fffu + ((x >> 16) & 1u)) >> 16;
    return (u16)r;
}
__device__ __forceinline__ float b2f(u16 b) {
    unsigned x = ((unsigned)b) << 16;
    return __builtin_bit_cast(float, x);
}

__device__ __forceinline__ void gl_lds16(const void* g, void* l) {
    __builtin_amdgcn_global_load_lds(
        (const __attribute__((address_space(1))) void*)g,
        (__attribute__((address_space(3))) void*)l, 16, 0, 0);
}

// ---- merged: prep (blocks 0..TT-1) + weight fp32->bf16 convert (blocks TT..) ----
// convert: one-shot, 8 elems/thread. prep: RMSNorm + router + s1/s3.
__global__ __launch_bounds__(256) void prep_f2b_k(const float* __restrict__ x,
                                                  const float* __restrict__ nw,
                                                  const float* __restrict__ gw,
                                                  const float* __restrict__ a1,
                                                  const float* __restrict__ a3,
                                                  const float* __restrict__ w1,
                                                  const float* __restrict__ w3,
                                                  const float* __restrict__ w2,
                                                  u16* __restrict__ tb,
                                                  float* __restrict__ topw,
                                                  int* __restrict__ topi,
                                                  float* __restrict__ s1,
                                                  float* __restrict__ s3,
                                                  u16* __restrict__ wB) {
    __shared__ float tL[DD];
    __shared__ float red[12];
    __shared__ int sE[2];
    int tid = threadIdx.x;

    if (blockIdx.x >= TT) {
        // ---- weight convert: seg = bid>>11 (w1/w3/w2), 2048 elems per block ----
        const int FD = FF * DD;
        int bid = blockIdx.x - TT;
        int seg = bid >> 11;
        const float* src = (seg == 0) ? w1 : ((seg == 1) ? w3 : w2);
        int off = (bid & 2047) * 2048 + tid * 8;
        float4 v0 = *(const float4*)(src + off);
        float4 v1 = *(const float4*)(src + off + 4);
        u16x8 o;
        o[0] = f2b(v0.x); o[1] = f2b(v0.y); o[2] = f2b(v0.z); o[3] = f2b(v0.w);
        o[4] = f2b(v1.x); o[5] = f2b(v1.y); o[6] = f2b(v1.z); o[7] = f2b(v1.w);
        *(u16x8*)(wB + (size_t)seg * FD + off) = o;
        return;
    }

    int tok = blockIdx.x;
    int wave = tid >> 6, lane = tid & 63;
    const float* xr = x + (size_t)tok * DD;
    // RMSNorm
    float xv[4];
    float ss = 0.f;
    #pragma unroll
    for (int i = 0; i < 4; i++) { xv[i] = xr[tid + 256 * i]; ss += xv[i] * xv[i]; }
    #pragma unroll
    for (int o = 32; o > 0; o >>= 1) ss += __shfl_down(ss, o);
    if (lane == 0) red[wave] = ss;
    __syncthreads();
    if (tid == 0) red[8] = rsqrtf((red[0] + red[1] + red[2] + red[3]) * (1.0f / DD) + EPSV);
    __syncthreads();
    float rs = red[8];
    #pragma unroll
    for (int i = 0; i < 4; i++) {
        float v = xv[i] * rs * nw[tid + 256 * i];
        tL[tid + 256 * i] = v;
        tb[(size_t)tok * DD + tid + 256 * i] = f2b(v);
    }
    __syncthreads();
    // Router: wave w -> experts 2w, 2w+1
    {
        const float* g0 = gw + (size_t)(2 * wave) * DD;
        const float* g1 = g0 + DD;
        float a0 = 0.f, a1v = 0.f;
        for (int d = lane; d < DD; d += 64) {
            float tv = tL[d];
            a0 = fmaf(tv, g0[d], a0);
            a1v = fmaf(tv, g1[d], a1v);
        }
        #pragma unroll
        for (int o = 32; o > 0; o >>= 1) { a0 += __shfl_down(a0, o); a1v += __shfl_down(a1v, o); }
        if (lane == 0) { red[2 * wave] = a0; red[2 * wave + 1] = a1v; }
    }
    __syncthreads();
    if (tid == 0) {
        float m = red[0];
        #pragma unroll
        for (int e = 1; e < EE; e++) m = fmaxf(m, red[e]);
        float p[EE];
        #pragma unroll
        for (int e = 0; e < EE; e++) p[e] = expf(red[e] - m);
        int i0 = 0; float v0 = p[0];
        for (int e = 1; e < EE; e++) if (p[e] > v0) { v0 = p[e]; i0 = e; }
        int i1 = -1; float v1 = -1.f;
        for (int e = 0; e < EE; e++) { if (e == i0) continue; if (p[e] > v1) { v1 = p[e]; i1 = e; } }
        float inv = 1.f / (v0 + v1);
        topi[tok * KKSEL + 0] = i0;
        topi[tok * KKSEL + 1] = i1;
        topw[tok * KKSEL + 0] = v0 * inv;
        topw[tok * KKSEL + 1] = v1 * inv;
        sE[0] = i0; sE[1] = i1;
    }
    __syncthreads();
    // s1/s3: wave w -> slot-half (w>>1), tensor (w&1)
    {
        int half = wave >> 1, ten = wave & 1;
        int slot = tok * 2 + half;
        int e = sE[half];
        const float* ap = ten ? a3 : a1;
        float* sp = ten ? s3 : s1;
        float tv[16];
        #pragma unroll
        for (int i = 0; i < 16; i++) tv[i] = tL[lane + 64 * i];
        const float* ab = ap + (size_t)e * RR * DD;
        #pragma unroll
        for (int r = 0; r < RR; r++) {
            const float* ar = ab + (size_t)r * DD;
            float c = 0.f;
            #pragma unroll
            for (int i = 0; i < 16; i++) c = fmaf(tv[i], ar[lane + 64 * i], c);
            #pragma unroll
            for (int o = 32; o > 0; o >>= 1) c += __shfl_down(c, o);
            if (lane == 0) sp[slot * RR + r] = SCALING * c;
        }
    }
}

// ---- expert-major LoRA-up delta + SwiGLU: actb[slot,f] = silu(h1+d1)*(h3+d3) ------
__global__ __launch_bounds__(256) void delta_act_k(const float* __restrict__ b1,
                                                   const float* __restrict__ b3,
                                                   const float* __restrict__ s1,
                                                   const float* __restrict__ s3,
                                                   const int* __restrict__ lists,
                                                   const int* __restrict__ counts,
                                                   const u16* __restrict__ hb,
                                                   u16* __restrict__ actb) {
    int e = blockIdx.y, f0 = blockIdx.x * DFC;
    int st = blockIdx.z * SCHUNK;
    int n = counts[e];
    if (st >= n) return;
    int gn = min(SCHUNK, n - st);
    __shared__ float bL[2][16 * 132];
    __shared__ float sG[2][SCHUNK * 16];
    __shared__ int   sSlot[SCHUNK];
    int tid = threadIdx.x;
    int g = tid >> 7, f = tid & 127;
    const int* lp = lists + e * 1024 + st;
    {
        const float* bsrc1 = b1 + ((size_t)e * FF + f0) * RR;
        const float* bsrc3 = b3 + ((size_t)e * FF + f0) * RR;
        #pragma unroll
        for (int i = tid; i < DFC * 16; i += 256) {
            int fi = i >> 4, r = i & 15;
            bL[0][r * 132 + fi] = bsrc1[i];
            bL[1][r * 132 + fi] = bsrc3[i];
        }
        int sl_l = (tid & 127) >> 2, q = tid & 3;
        if (sl_l < gn) {
            int slot = lp[sl_l];
            const float* ssrc = g ? s3 : s1;
            *(float4*)&sG[g][sl_l * 16 + q * 4] = *(const float4*)&ssrc[slot * RR + q * 4];
            if (g == 0 && q == 0) sSlot[sl_l] = slot;
        }
    }
    __syncthreads();
    for (int ii = g; ii < gn; ii += 2) {
        int slot = sSlot[ii];
        int tok = slot >> 1;
        float h1b = b2f(hb[(size_t)tok * (2 * FF) + f0 + f]);
        float h3b = b2f(hb[(size_t)tok * (2 * FF) + FF + f0 + f]);
        const float* sp1 = &sG[0][ii * 16];
        const float* sp3 = &sG[1][ii * 16];
        float d1 = 0.f, d3 = 0.f;
        #pragma unroll
        for (int r = 0; r < RR; r++) {
            d1 = fmaf(sp1[r], bL[0][r * 132 + f], d1);
            d3 = fmaf(sp3[r], bL[1][r * 132 + f], d3);
        }
        float h1 = h1b + d1, h3 = h3b + d3;
        float sig = 1.f / (1.f + expf(-h1));
        actb[(size_t)slot * FF + f0 + f] = f2b(h1 * sig * h3);
    }
}

// ---------------- generic NT GEMM, 64x128 tile, BK=32, 3-deep pipelined LDS ----------
// LISTS: last y-row (x==0) runs build_lists instead of GEMM (overlapped, no dependency).
template<int SPLITK, bool BF16OUT, bool LISTS>
__global__ __launch_bounds__(256) void gemm_nt(const u16* __restrict__ A,
                                               const u16* __restrict__ B,
                                               void* __restrict__ Cv,
                                               int M, int N, int K,
                                               const int* __restrict__ topi,
                                               int* __restrict__ lists,
                                               int* __restrict__ counts) {
    __shared__ u16 As[3][64 * 32];
    __shared__ u16 Bs[3][128 * 32];
    int tid = threadIdx.x;

    if (LISTS && blockIdx.y == gridDim.y - 1) {
        if (blockIdx.x == 0) {
            int* cnt = (int*)&As[0][0];
            if (tid < EE) cnt[tid] = 0;
            __syncthreads();
            for (int s = tid; s < TT * KKSEL; s += 256) atomicAdd(&cnt[topi[s]], 1);
            __syncthreads();
            if (tid < EE) { counts[tid] = cnt[tid]; cnt[tid] = 0; }
            __syncthreads();
            for (int s = tid; s < TT * KKSEL; s += 256) {
                int e = topi[s];
                int p = atomicAdd(&cnt[e], 1);
                lists[e * 1024 + p] = s;
            }
        }
        return;
    }

    int w = tid >> 6, lane = tid & 63;
    int wr = w >> 1, wc = w & 1;            // wave tile: 32(M) x 64(N)
    int lr = lane & 15, ks = lane >> 4;
    int z = (SPLITK > 1) ? blockIdx.z : 0;
    int kc = K / SPLITK;
    int k0s = z * kc;
    int nk = kc / 32;
    int m0 = blockIdx.y * 64, n0 = blockIdx.x * 128;

    int row = tid >> 2;            // 0..63
    int inb = (tid & 3) * 16;
    size_t rb = (size_t)K * 2;
    const char* Ag  = (const char*)A + (size_t)(m0 + row) * rb + inb + (size_t)k0s * 2;
    const char* Bg  = (const char*)B + (size_t)(n0 + row) * rb + inb + (size_t)k0s * 2;
    const char* Bg2 = Bg + 64 * rb;

    floatx4 zero4 = {0.f, 0.f, 0.f, 0.f};
    floatx4 acc[2][4];
    #pragma unroll
    for (int i = 0; i < 2; i++)
        #pragma unroll
        for (int j = 0; j < 4; j++) acc[i][j] = zero4;

    auto stage = [&](int buf, int kt) {
        size_t kb = (size_t)kt * 64;   // 32 elems * 2B
        gl_lds16(Ag + kb, &As[buf][w * 512]);
        gl_lds16(Bg + kb, &Bs[buf][w * 512]);
        gl_lds16(Bg2 + kb, &Bs[buf][2048 + w * 512]);
    };
    auto compute = [&](int buf) {
        bhalf8 af[2], bf[4];
        #pragma unroll
        for (int i = 0; i < 2; i++)
            af[i] = *(const bhalf8*)&As[buf][(wr * 32 + i * 16 + lr) * 32 + ks * 8];
        #pragma unroll
        for (int j = 0; j < 4; j++)
            bf[j] = *(const bhalf8*)&Bs[buf][(wc * 64 + j * 16 + lr) * 32 + ks * 8];
        #pragma unroll
        for (int i = 0; i < 2; i++)
            #pragma unroll
            for (int j = 0; j < 4; j++)
                acc[i][j] = __builtin_amdgcn_mfma_f32_16x16x32_bf16(af[i], bf[j], acc[i][j], 0, 0, 0);
    };

    stage(0, 0);
    stage(1, 1);
    asm volatile("s_waitcnt vmcnt(3)" ::: "memory");
    __builtin_amdgcn_s_barrier();

    int cur = 0;
    for (int kt = 0; kt < nk; ++kt) {
        int pre = cur + 2; if (pre >= 3) pre -= 3;
        if (kt + 2 < nk) stage(pre, kt + 2);
        compute(cur);
        asm volatile("s_waitcnt lgkmcnt(0)" ::: "memory");
        if (kt + 1 < nk) {
            if (kt + 2 < nk) asm volatile("s_waitcnt vmcnt(3)" ::: "memory");
            else             asm volatile("s_waitcnt vmcnt(0)" ::: "memory");
            __builtin_amdgcn_s_barrier();
        }
        cur = (cur + 1 == 3) ? 0 : cur + 1;
    }

    int crow = (lane >> 4) * 4;
    #pragma unroll
    for (int i = 0; i < 2; i++) {
        #pragma unroll
        for (int j = 0; j < 4; j++) {
            int r0 = m0 + wr * 32 + i * 16 + crow;
            int c0 = n0 + wc * 64 + j * 16 + lr;
            if (BF16OUT) {
                u16* Cb = (u16*)Cv;
                #pragma unroll
                for (int mm = 0; mm < 4; mm++)
                    Cb[(size_t)(r0 + mm) * N + c0] = f2b(acc[i][j][mm]);
            } else {
                float* Cf = (float*)Cv + (size_t)z * M * N;
                #pragma unroll
                for (int mm = 0; mm < 4; mm++)
                    Cf[(size_t)(r0 + mm) * N + c0] = acc[i][j][mm];
            }
        }
    }
}

// ---- s2 (both slots of a token) + mixed[t,f] = w0*act[2t,f] + w1*act[2t+1,f] -------
__global__ __launch_bounds__(256) void s2mix_k(const u16* __restrict__ actb,
                                               const float* __restrict__ a2,
                                               const int* __restrict__ topi,
                                               const float* __restrict__ topw,
                                               float* __restrict__ s2,
                                               u16* __restrict__ mixedb) {
    int tok = blockIdx.x;
    int tid = threadIdx.x, wave = tid >> 6, lane = tid & 63;
    int slot = tok * 2 + (wave >> 1);
    int e = topi[slot];
    const u16* ar = actb + (size_t)slot * FF;
    float av[64];
    #pragma unroll
    for (int i = 0; i < 16; i++) {
        ushort4 u = *(const ushort4*)(ar + lane * 4 + 256 * i);
        av[i * 4 + 0] = b2f(u.x); av[i * 4 + 1] = b2f(u.y);
        av[i * 4 + 2] = b2f(u.z); av[i * 4 + 3] = b2f(u.w);
    }
    #pragma unroll
    for (int rr = 0; rr < 8; rr++) {
        int r = (wave & 1) * 8 + rr;
        const float* a2p = a2 + ((size_t)e * RR + r) * FF;
        float c = 0.f;
        #pragma unroll
        for (int i = 0; i < 16; i++) {
            float4 w4 = *(const float4*)(a2p + lane * 4 + 256 * i);
            c = fmaf(av[i * 4 + 0], w4.x, c);
            c = fmaf(av[i * 4 + 1], w4.y, c);
            c = fmaf(av[i * 4 + 2], w4.z, c);
            c = fmaf(av[i * 4 + 3], w4.w, c);
        }
        #pragma unroll
        for (int o = 32; o > 0; o >>= 1) c += __shfl_down(c, o);
        if (lane == 0) s2[slot * RR + r] = SCALING * c;
    }
    // mixed (coalesced, independent of the above)
    float w0 = topw[tok * 2], w1v = topw[tok * 2 + 1];
    const u16* a0 = actb + (size_t)(tok * 2) * FF;
    const u16* a1p = a0 + FF;
    #pragma unroll
    for (int it = 0; it < 2; it++) {
        int f = tid * 8 + it * 2048;
        u16x8 v0 = *(const u16x8*)(a0 + f);
        u16x8 v1 = *(const u16x8*)(a1p + f);
        u16x8 o;
        #pragma unroll
        for (int q = 0; q < 8; q++)
            o[q] = f2b(w0 * b2f(v0[q]) + w1v * b2f(v1[q]));
        *(u16x8*)(mixedb + (size_t)tok * FF + f) = o;
    }
}

// ---- combine: out[t,d] = sum_z downP[z,t,d] + sum_k w_k * (s2[slot_k] . b2[e_k,d,:]) --
__global__ __launch_bounds__(256) void combine_k(const float* __restrict__ downP,
                                                 const float* __restrict__ s2,
                                                 const float* __restrict__ b2,
                                                 const float* __restrict__ topw,
                                                 const int* __restrict__ topi,
                                                 float* __restrict__ out) {
    int tok = blockIdx.x;
    for (int d = threadIdx.x; d < DD; d += 256) {
        float v = 0.f;
        #pragma unroll
        for (int zz = 0; zz < 8; zz++)
            v += downP[(size_t)zz * TT * DD + (size_t)tok * DD + d];
        #pragma unroll
        for (int k = 0; k < KKSEL; k++) {
            int slot = tok * KKSEL + k;
            int e = topi[slot];
            float w = topw[slot];
            const float* b2p = b2 + ((size_t)e * DD + d) * RR;
            const float* s2p = s2 + slot * RR;
            float l = 0.f;
            #pragma unroll
            for (int r = 0; r < RR; r++) l = fmaf(s2p[r], b2p[r], l);
            v += w * l;
        }
        out[(size_t)tok * DD + d] = v;
    }
}

extern "C" void kernel_launch(void* const* d_in, const int* in_sizes, int n_in,
                              void* d_out, int out_size, void* d_ws, size_t ws_size,
                              hipStream_t stream) {
    const float* x  = (const float*)d_in[0];
    const float* nw = (const float*)d_in[1];
    const float* w1 = (const float*)d_in[2];
    const float* w3 = (const float*)d_in[3];
    const float* w2 = (const float*)d_in[4];
    const float* gw = (const float*)d_in[5];
    const float* a1 = (const float*)d_in[6];
    const float* b1 = (const float*)d_in[7];
    const float* a3 = (const float*)d_in[8];
    const float* b3 = (const float*)d_in[9];
    const float* a2 = (const float*)d_in[10];
    const float* b2 = (const float*)d_in[11];
    float* out = (float*)d_out;

    // workspace layout (~61 MB), all chunks 16B-aligned
    float* downP = (float*)d_ws;                          // 8 * 512*1024 f32 (16MB)
    float* s1    = downP + (size_t)8 * TT * DD;
    float* s3    = s1 + (size_t)TT * KKSEL * RR;
    float* s2    = s3 + (size_t)TT * KKSEL * RR;
    float* topw  = s2 + (size_t)TT * KKSEL * RR;
    int*   topi  = (int*)(topw + TT * KKSEL);
    int*   lists = topi + TT * KKSEL;                     // 8*1024
    int*   counts= lists + EE * 1024;                     // 16
    u16*   tb    = (u16*)(counts + 16);                   // 512*1024
    u16*   wB    = tb + (size_t)TT * DD;                  // [w1b | w3b | w2b] 3*4096*1024
    u16*   w2b   = wB + (size_t)2 * FF * DD;
    u16*   hb    = w2b + (size_t)DD * FF;                 // 512*8192 (h1|h3 per token)
    u16*   actb  = hb + (size_t)TT * 2 * FF;              // 1024*4096
    u16*   mixedb= actb + (size_t)TT * KKSEL * FF;        // 512*4096

    // prep (512 blocks) + weight convert (6144 one-shot blocks) in one launch
    prep_f2b_k<<<TT + CVTB, 256, 0, stream>>>(
        x, nw, gw, a1, a3, w1, w3, w2, tb, topw, topi, s1, s3, wB);
    // h[tok, 0:4096]=t@w1^T, h[tok, 4096:8192]=t@w3^T (512 GEMM blocks)
    // + build_lists in the extra y-row (overlapped, no dependency)
    gemm_nt<1, true, true><<<dim3(2 * FF / 128, TT / 64 + 1), 256, 0, stream>>>(
        tb, wB, hb, TT, 2 * FF, DD, topi, lists, counts);
    delta_act_k<<<dim3(FF / DFC, EE, 32), 256, 0, stream>>>(
        b1, b3, s1, s3, lists, counts, hb, actb);
    s2mix_k<<<TT, 256, 0, stream>>>(actb, a2, topi, topw, s2, mixedb);
    // down base on mixed: M=512, split-K=8, 512 blocks
    gemm_nt<8, false, false><<<dim3(DD / 128, TT / 64, 8), 256, 0, stream>>>(
        mixedb, w2b, downP, TT, DD, FF, nullptr, nullptr, nullptr);
    combine_k<<<TT, 256, 0, stream>>>(downP, s2, b2, topw, topi, out);
}